// Round 13
// baseline (31.367 us; speedup 1.0000x reference)
//
#include <hip/hip_runtime.h>

typedef __attribute__((ext_vector_type(8))) short bf16x8;
typedef __attribute__((ext_vector_type(4))) float f32x4;

#define C_DIM 512
#define HID   256
#define B_DIM 8
#define L_DIM 196
#define MTPB  7                 // m-tiles per batch (7*32 = 224 >= 196, tail masked)
#define NT    32                // n cols per tile
#define GEMM_BLOCKS (B_DIM*MTPB*8*2)        // 896
#define ROWS  14                // i-rows per wave (phase 2)
#define NJC   14                // j-chunks (phase 2)
#define JCL   (L_DIM/NJC)       // 14
#define PAIR_BLOCKS ((B_DIM*NJC*ROWS)/4)    // 392 = 49*8
#define P_ELEMS (B_DIM*L_DIM*HID)
#define FT_ROWS (2*B_DIM*L_DIM)             // 3136 rows of 512 bf16
#define WT_ROWS (2*HID)                     // 512 rows of 512 bf16

// f32 -> bf16 bits, round-to-nearest (ties up): 2 VALU ops
__device__ __forceinline__ short bf16r(float x) {
  unsigned u = __builtin_bit_cast(unsigned, x);
  return (short)((u + 0x8000u) >> 16);
}

// Prep: transpose+convert to k-minor bf16 so MFMA fragments load as dwordx4.
//   fT[side][r=b*196+l][c] = bf16(f_side[b][c][l])   (rows of 512, 1KB)
//   WT[side][h][c]         = bf16(W1[side*512+c][h])
// Per wave: 8 coalesced f32 loads (lane = l or h) + ONE 16B scatter-store.
// f-blocks XCD-local: bid&7 = b. l-chunks {0,64,128,132} (overlap benign).
__global__ __launch_bounds__(256) void prep_kernel(
    const float* __restrict__ f1, const float* __restrict__ f2,
    const float* __restrict__ W1,
    unsigned short* __restrict__ fT, unsigned short* __restrict__ WT) {
  const int w    = threadIdx.x >> 6;
  const int lane = threadIdx.x & 63;
  const int bid  = blockIdx.x;
  if (bid < 1024) {                             // f tasks: (side, b, co, lc=w)
    const int b    = bid & 7;                   // XCD-co-located batch
    const int idx  = bid >> 3;                  // 0..127
    const int side = idx >> 6;
    const int co   = idx & 63;                  // c-octet 0..63
    const int l0   = (w < 3) ? w * 64 : 132;    // {0,64,128,132}
    const int l    = l0 + lane;                 // < 196 always
    const float* __restrict__ f = side ? f2 : f1;
    const float* __restrict__ src = f + (b * C_DIM + co * 8) * L_DIM + l;
    bf16x8 v;
    #pragma unroll
    for (int i = 0; i < 8; ++i) v[i] = bf16r(src[i * L_DIM]);   // coalesced
    *(bf16x8*)(fT + ((size_t)(side * (B_DIM * L_DIM) + b * L_DIM + l) << 9)
                  + co * 8) = v;                // one 16B scatter-store
  } else {                                      // W tasks: (side, co, hc=w)
    const int wid  = bid - 1024;                // 0..127
    const int side = wid >> 6;
    const int co   = wid & 63;
    const int h    = w * 64 + lane;             // < 256
    const float* __restrict__ src = W1 + (side * C_DIM + co * 8) * HID + h;
    bf16x8 v;
    #pragma unroll
    for (int i = 0; i < 8; ++i) v[i] = bf16r(src[i * HID]);     // coalesced
    *(bf16x8*)(WT + ((size_t)(side * HID + h) << 9) + co * 8) = v;
  }
}

// Phase 1 v5 (r12 structure, fragment loads = single dwordx4 from fT/WT):
//   p[b,l,h] = sum_c f[b,c,l] * W[c,h]   (+ b1[h] for side 0)
// wgid = idx*8 + b -> all blocks of batch b on XCD b. Block = 4 waves =
// 4 k-quarters of one 32m x 32n tile; LDS tree-combine. 4 loads + 4 MFMA/kstep.
__global__ __launch_bounds__(256) void gemm_p_mfma(
    const unsigned short* __restrict__ fT, const unsigned short* __restrict__ WT,
    const float* __restrict__ b1, const float* __restrict__ b2,
    float* __restrict__ p1, float* __restrict__ p2,
    float* __restrict__ out) {
  // init output accumulators (pair_kernel atomicAdds into them)
  if (blockIdx.x == 0 && threadIdx.x < B_DIM)
    out[threadIdx.x] = (float)(L_DIM * L_DIM) * b2[0];

  const int wgid = blockIdx.x;                  // 0..895
  const int b    = wgid & 7;                    // XCD-co-located batch
  const int idx  = wgid >> 3;                   // 0..111
  const int nt   = idx & 7;                     // n-tile 0..7
  const int ms   = idx >> 3;                    // 0..13
  const int side = ms & 1;
  const int mt   = ms >> 1;                     // m-tile within b, 0..6

  float* __restrict__ p = side ? p2 : p1;

  const int tid  = threadIdx.x;
  const int kq   = tid >> 6;                    // wave = k-quarter 0..3
  const int lane = tid & 63;
  const int g    = lane >> 4;                   // k-subgroup 0..3
  const int mcol = lane & 15;

  // fT row indices (tail rows >=196 clamped, masked at store)
  int rowA[2];
  #pragma unroll
  for (int mi = 0; mi < 2; ++mi) {
    const int rib = mt * 32 + mi * 16 + mcol;   // 0..223
    const int l = rib < L_DIM ? rib : L_DIM - 1;
    rowA[mi] = side * (B_DIM * L_DIM) + b * L_DIM + l;
  }
  const int h0 = nt * NT + mcol;                // + ni*16

  f32x4 acc[2][2];
  #pragma unroll
  for (int mi = 0; mi < 2; ++mi)
    #pragma unroll
    for (int ni = 0; ni < 2; ++ni)
      acc[mi][ni] = (f32x4){0.f, 0.f, 0.f, 0.f};

  #pragma unroll
  for (int ks = 0; ks < 4; ++ks) {
    const int k0 = kq * 128 + ks * 32 + g * 8;  // this lane's 8 k's
    bf16x8 afr[2], bfr[2];
    #pragma unroll
    for (int mi = 0; mi < 2; ++mi)
      afr[mi] = *(const bf16x8*)(fT + ((size_t)rowA[mi] << 9) + k0);
    #pragma unroll
    for (int ni = 0; ni < 2; ++ni)
      bfr[ni] = *(const bf16x8*)(WT + ((size_t)(side * HID + h0 + ni * 16) << 9) + k0);
    #pragma unroll
    for (int mi = 0; mi < 2; ++mi)
      #pragma unroll
      for (int ni = 0; ni < 2; ++ni)
        acc[mi][ni] = __builtin_amdgcn_mfma_f32_16x16x32_bf16(
            afr[mi], bfr[ni], acc[mi][ni], 0, 0, 0);
  }

  // tree-combine 4 k-quarter waves (flattened idx = mi*8 + ni*4 + reg)
  __shared__ float comb[2][64][17];             // 8.7 KB, 17-stride
  if (kq >= 2) {
    #pragma unroll
    for (int mi = 0; mi < 2; ++mi)
      #pragma unroll
      for (int ni = 0; ni < 2; ++ni)
        *(float4*)&comb[kq - 2][lane][mi * 8 + ni * 4] =
            *(float4*)&acc[mi][ni];
  }
  __syncthreads();
  if (kq < 2) {
    #pragma unroll
    for (int mi = 0; mi < 2; ++mi)
      #pragma unroll
      for (int ni = 0; ni < 2; ++ni) {
        const float4 o = *(const float4*)&comb[kq][lane][mi * 8 + ni * 4];
        acc[mi][ni][0] += o.x; acc[mi][ni][1] += o.y;
        acc[mi][ni][2] += o.z; acc[mi][ni][3] += o.w;
      }
  }
  __syncthreads();
  if (kq == 1) {
    #pragma unroll
    for (int mi = 0; mi < 2; ++mi)
      #pragma unroll
      for (int ni = 0; ni < 2; ++ni)
        *(float4*)&comb[0][lane][mi * 8 + ni * 4] = *(float4*)&acc[mi][ni];
  }
  __syncthreads();
  if (kq == 0) {
    // C/D layout (verified): col = lane&15, row = g*4 + reg
    #pragma unroll
    for (int mi = 0; mi < 2; ++mi) {
      const int rib0 = mt * 32 + mi * 16 + g * 4;
      #pragma unroll
      for (int ni = 0; ni < 2; ++ni) {
        const int h = h0 + ni * 16;
        const float bias = side ? 0.0f : b1[h];
        const float4 o = *(const float4*)&comb[0][lane][mi * 8 + ni * 4];
        const float v0 = acc[mi][ni][0] + o.x + bias;
        const float v1 = acc[mi][ni][1] + o.y + bias;
        const float v2 = acc[mi][ni][2] + o.z + bias;
        const float v3 = acc[mi][ni][3] + o.w + bias;
        if (rib0 + 0 < L_DIM) p[(b * L_DIM + rib0 + 0) * HID + h] = v0;
        if (rib0 + 1 < L_DIM) p[(b * L_DIM + rib0 + 1) * HID + h] = v1;
        if (rib0 + 2 < L_DIM) p[(b * L_DIM + rib0 + 2) * HID + h] = v2;
        if (rib0 + 3 < L_DIM) p[(b * L_DIM + rib0 + 3) * HID + h] = v3;
      }
    }
  }
}

// Phase 2 (r12 exact): wgid = idx*8 + b -> XCD-local; wave = 14 i x 14 j;
// block-sum -> ONE atomicAdd into out[b].
__global__ __launch_bounds__(256) void pair_kernel(
    const float* __restrict__ p1, const float* __restrict__ p2,
    const float* __restrict__ W2, float* __restrict__ out) {
  const int lane = threadIdx.x & 63;
  const int w    = threadIdx.x >> 6;
  const int b    = blockIdx.x & 7;              // XCD-co-located batch
  const int idx  = blockIdx.x >> 3;             // 0..48
  const int r4   = idx * 4 + w;                 // 0..195
  const int jc   = r4 / ROWS;                   // 0..13
  const int wi   = r4 % ROWS;                   // 0..13

  const float4 wv = *(const float4*)(W2 + lane * 4);
  const float* __restrict__ p1b = p1 + (b * L_DIM) * HID + lane * 4;

  float4 a[ROWS];
  #pragma unroll
  for (int k = 0; k < ROWS; ++k)
    a[k] = *(const float4*)(p1b + (wi + k * ROWS) * HID);  // i = wi + k*14

  float s[ROWS];
  #pragma unroll
  for (int k = 0; k < ROWS; ++k) s[k] = 0.0f;

  const float4* __restrict__ vp =
      (const float4*)(p2 + (b * L_DIM + jc * JCL) * HID) + lane;

#define PAIR_BODY(vv)                                            \
  {                                                              \
    _Pragma("unroll")                                            \
    for (int k = 0; k < ROWS; ++k) {                             \
      s[k] = fmaf(fmaxf(a[k].x + (vv).x, 0.f), wv.x, s[k]);      \
      s[k] = fmaf(fmaxf(a[k].y + (vv).y, 0.f), wv.y, s[k]);      \
      s[k] = fmaf(fmaxf(a[k].z + (vv).z, 0.f), wv.z, s[k]);      \
      s[k] = fmaf(fmaxf(a[k].w + (vv).w, 0.f), wv.w, s[k]);      \
    }                                                            \
  }

  // two 7-deep batches: 7 loads in flight, then compute
  float4 vv[7];
  #pragma unroll
  for (int j = 0; j < 7; ++j) vv[j] = vp[j * (HID / 4)];
  #pragma unroll
  for (int j = 0; j < 7; ++j) PAIR_BODY(vv[j]);
  #pragma unroll
  for (int j = 0; j < 7; ++j) vv[j] = vp[(7 + j) * (HID / 4)];
  #pragma unroll
  for (int j = 0; j < 7; ++j) PAIR_BODY(vv[j]);
#undef PAIR_BODY

  // collapse rows (13 adds), then one 6-step wave reduce
  float t = 0.0f;
  #pragma unroll
  for (int k = 0; k < ROWS; ++k) t += s[k];
  #pragma unroll
  for (int off = 32; off > 0; off >>= 1) t += __shfl_down(t, off);

  __shared__ float sred[4];
  if (lane == 0) sred[w] = t;
  __syncthreads();
  if (threadIdx.x == 0)
    atomicAdd(&out[b], sred[0] + sred[1] + sred[2] + sred[3]);  // 392 total
}

extern "C" void kernel_launch(void* const* d_in, const int* in_sizes, int n_in,
                              void* d_out, int out_size, void* d_ws, size_t ws_size,
                              hipStream_t stream) {
  const float* f1 = (const float*)d_in[0];   // [B, C, 14, 14]
  const float* f2 = (const float*)d_in[1];
  const float* W1 = (const float*)d_in[2];   // [2C, HID]
  const float* b1 = (const float*)d_in[3];   // [HID]
  const float* W2 = (const float*)d_in[4];   // [HID, 1]
  const float* b2 = (const float*)d_in[5];   // [1]
  float* out = (float*)d_out;                // [B, 1]

  float* p1 = (float*)d_ws;
  float* p2 = p1 + P_ELEMS;
  unsigned short* fT = (unsigned short*)(p2 + P_ELEMS);   // 3136 x 512 bf16
  unsigned short* WT = fT + (size_t)FT_ROWS * 512;        // 512 x 512 bf16

  prep_kernel<<<1152, 256, 0, stream>>>(f1, f2, W1, fT, WT);

  gemm_p_mfma<<<GEMM_BLOCKS, 256, 0, stream>>>(fT, WT, b1, b2, p1, p2, out);

  pair_kernel<<<PAIR_BLOCKS, 256, 0, stream>>>(p1, p2, W2, out);
}

// Round 14
// 27.198 us; speedup vs baseline: 1.1533x; 1.1533x over previous
//
#include <hip/hip_runtime.h>

typedef __attribute__((ext_vector_type(8))) short bf16x8;
typedef __attribute__((ext_vector_type(4))) float f32x4;

#define C_DIM 512
#define HID   256
#define B_DIM 8
#define L_DIM 196
#define MTPB  7                 // m-tiles per batch (7*32 = 224 >= 196, tail masked)
#define NT    32                // n cols per tile
#define NNT   (HID/NT)          // 8 n-tiles
#define GEMM_BLOCKS (B_DIM*MTPB*NNT*2)      // 896 = 112*8
#define ROWS  14                // i-rows per wave (phase 2)
#define NJC   14                // j-chunks (phase 2)
#define JCL   (L_DIM/NJC)       // 14
#define PAIR_BLOCKS ((B_DIM*NJC*ROWS)/4)    // 392 = 49*8
#define P_ELEMS (B_DIM*L_DIM*HID)

// f32 -> bf16 bits, round-to-nearest (ties up): 2 VALU ops
__device__ __forceinline__ short bf16r(float x) {
  unsigned u = __builtin_bit_cast(unsigned, x);
  return (short)((u + 0x8000u) >> 16);
}

// Phase 1 (r12 exact): MFMA bf16, K-split x4, XCD-local per batch.
//   p[b,l,h] = sum_c f[b,c,l] * W[c,h]   (+ b1[h] for side 0)
// wgid = idx*8 + b  ->  all blocks of batch b on XCD b (round-robin dispatch).
// Block = 4 waves = 4 k-quarters of one 32m x 32n tile; LDS tree-combine.
__global__ __launch_bounds__(256) void gemm_p_mfma(
    const float* __restrict__ f1, const float* __restrict__ f2,
    const float* __restrict__ W1, const float* __restrict__ b1,
    const float* __restrict__ b2,
    float* __restrict__ p1, float* __restrict__ p2,
    float* __restrict__ out) {
  // init output accumulators (pair_kernel atomicAdds into them)
  if (blockIdx.x == 0 && threadIdx.x < B_DIM)
    out[threadIdx.x] = (float)(L_DIM * L_DIM) * b2[0];

  const int wgid = blockIdx.x;                  // 0..895
  const int b    = wgid & 7;                    // XCD-co-located batch
  const int idx  = wgid >> 3;                   // 0..111
  const int nt   = idx & 7;                     // n-tile 0..7
  const int ms   = idx >> 3;                    // 0..13
  const int side = ms & 1;
  const int mt   = ms >> 1;                     // m-tile within b, 0..6

  const float* __restrict__ f = side ? f2 : f1;
  const float* __restrict__ W = W1 + side * C_DIM * HID;
  float* __restrict__ p = side ? p2 : p1;

  const int tid  = threadIdx.x;
  const int kq   = tid >> 6;                    // wave = k-quarter 0..3
  const int lane = tid & 63;
  const int g    = lane >> 4;                   // k-subgroup 0..3
  const int mcol = lane & 15;

  // A row bases within batch b (tail rows >=196 clamped, masked at store)
  int aoff[2];
  #pragma unroll
  for (int mi = 0; mi < 2; ++mi) {
    const int rib = mt * 32 + mi * 16 + mcol;   // 0..223
    const int l = rib < L_DIM ? rib : L_DIM - 1;
    aoff[mi] = (b * C_DIM) * L_DIM + l;
  }
  const int h0 = nt * NT + mcol;                // + ni*16

  f32x4 acc[2][2];
  #pragma unroll
  for (int mi = 0; mi < 2; ++mi)
    #pragma unroll
    for (int ni = 0; ni < 2; ++ni)
      acc[mi][ni] = (f32x4){0.f, 0.f, 0.f, 0.f};

  #pragma unroll
  for (int ks = 0; ks < 4; ++ks) {
    const int k0 = kq * 128 + ks * 32 + g * 8;  // this lane's 8 k's
    bf16x8 afr[2], bfr[2];
    #pragma unroll
    for (int mi = 0; mi < 2; ++mi) {
      const float* __restrict__ pa = f + aoff[mi] + k0 * L_DIM;
      #pragma unroll
      for (int i = 0; i < 8; ++i) afr[mi][i] = bf16r(pa[i * L_DIM]);
    }
    #pragma unroll
    for (int ni = 0; ni < 2; ++ni) {
      const float* __restrict__ pb = W + k0 * HID + h0 + ni * 16;
      #pragma unroll
      for (int i = 0; i < 8; ++i) bfr[ni][i] = bf16r(pb[i * HID]);
    }
    #pragma unroll
    for (int mi = 0; mi < 2; ++mi)
      #pragma unroll
      for (int ni = 0; ni < 2; ++ni)
        acc[mi][ni] = __builtin_amdgcn_mfma_f32_16x16x32_bf16(
            afr[mi], bfr[ni], acc[mi][ni], 0, 0, 0);
  }

  // tree-combine 4 k-quarter waves (flattened idx = mi*8 + ni*4 + reg)
  __shared__ float comb[2][64][17];             // 8.7 KB, 17-stride
  if (kq >= 2) {
    #pragma unroll
    for (int mi = 0; mi < 2; ++mi)
      #pragma unroll
      for (int ni = 0; ni < 2; ++ni)
        *(float4*)&comb[kq - 2][lane][mi * 8 + ni * 4] =
            *(float4*)&acc[mi][ni];
  }
  __syncthreads();
  if (kq < 2) {
    #pragma unroll
    for (int mi = 0; mi < 2; ++mi)
      #pragma unroll
      for (int ni = 0; ni < 2; ++ni) {
        const float4 o = *(const float4*)&comb[kq][lane][mi * 8 + ni * 4];
        acc[mi][ni][0] += o.x; acc[mi][ni][1] += o.y;
        acc[mi][ni][2] += o.z; acc[mi][ni][3] += o.w;
      }
  }
  __syncthreads();
  if (kq == 1) {
    #pragma unroll
    for (int mi = 0; mi < 2; ++mi)
      #pragma unroll
      for (int ni = 0; ni < 2; ++ni)
        *(float4*)&comb[0][lane][mi * 8 + ni * 4] = *(float4*)&acc[mi][ni];
  }
  __syncthreads();
  if (kq == 0) {
    // C/D layout (verified): col = lane&15, row = g*4 + reg
    #pragma unroll
    for (int mi = 0; mi < 2; ++mi) {
      const int rib0 = mt * 32 + mi * 16 + g * 4;
      #pragma unroll
      for (int ni = 0; ni < 2; ++ni) {
        const int h = h0 + ni * 16;
        const float bias = side ? 0.0f : b1[h];
        const float4 o = *(const float4*)&comb[0][lane][mi * 8 + ni * 4];
        const float v0 = acc[mi][ni][0] + o.x + bias;
        const float v1 = acc[mi][ni][1] + o.y + bias;
        const float v2 = acc[mi][ni][2] + o.z + bias;
        const float v3 = acc[mi][ni][3] + o.w + bias;
        // tail mask (only mt=6 has rows >=196)
        if (rib0 + 0 < L_DIM) p[(b * L_DIM + rib0 + 0) * HID + h] = v0;
        if (rib0 + 1 < L_DIM) p[(b * L_DIM + rib0 + 1) * HID + h] = v1;
        if (rib0 + 2 < L_DIM) p[(b * L_DIM + rib0 + 2) * HID + h] = v2;
        if (rib0 + 3 < L_DIM) p[(b * L_DIM + rib0 + 3) * HID + h] = v3;
      }
    }
  }
}

// Phase 2 (r12 body; __launch_bounds__(256,1) so a[]/vv[]/s[] stay in VGPRs —
// r3/r12's VGPR_Count=36 proves the compiler was sinking the 14 a-row loads
// into the j-loop at default occupancy targets).
// wgid = idx*8 + b -> XCD-local; wave = 14 i x 14 j; block-sum -> ONE atomicAdd.
__global__ __launch_bounds__(256, 1) void pair_kernel(
    const float* __restrict__ p1, const float* __restrict__ p2,
    const float* __restrict__ W2, float* __restrict__ out) {
  const int lane = threadIdx.x & 63;
  const int w    = threadIdx.x >> 6;
  const int b    = blockIdx.x & 7;              // XCD-co-located batch
  const int idx  = blockIdx.x >> 3;             // 0..48
  const int r4   = idx * 4 + w;                 // 0..195
  const int jc   = r4 / ROWS;                   // 0..13
  const int wi   = r4 % ROWS;                   // 0..13

  const float4 wv = *(const float4*)(W2 + lane * 4);
  const float* __restrict__ p1b = p1 + (b * L_DIM) * HID + lane * 4;

  float4 a[ROWS];
  #pragma unroll
  for (int k = 0; k < ROWS; ++k)
    a[k] = *(const float4*)(p1b + (wi + k * ROWS) * HID);  // i = wi + k*14

  float s[ROWS];
  #pragma unroll
  for (int k = 0; k < ROWS; ++k) s[k] = 0.0f;

  const float4* __restrict__ vp =
      (const float4*)(p2 + (b * L_DIM + jc * JCL) * HID) + lane;

#define PAIR_BODY(vv)                                            \
  {                                                              \
    _Pragma("unroll")                                            \
    for (int k = 0; k < ROWS; ++k) {                             \
      s[k] = fmaf(fmaxf(a[k].x + (vv).x, 0.f), wv.x, s[k]);      \
      s[k] = fmaf(fmaxf(a[k].y + (vv).y, 0.f), wv.y, s[k]);      \
      s[k] = fmaf(fmaxf(a[k].z + (vv).z, 0.f), wv.z, s[k]);      \
      s[k] = fmaf(fmaxf(a[k].w + (vv).w, 0.f), wv.w, s[k]);      \
    }                                                            \
  }

  // two 7-deep batches: 7 loads in flight, then compute
  float4 vv[7];
  #pragma unroll
  for (int j = 0; j < 7; ++j) vv[j] = vp[j * (HID / 4)];
  #pragma unroll
  for (int j = 0; j < 7; ++j) PAIR_BODY(vv[j]);
  #pragma unroll
  for (int j = 0; j < 7; ++j) vv[j] = vp[(7 + j) * (HID / 4)];
  #pragma unroll
  for (int j = 0; j < 7; ++j) PAIR_BODY(vv[j]);
#undef PAIR_BODY

  // collapse rows (13 adds), then one 6-step wave reduce
  float t = 0.0f;
  #pragma unroll
  for (int k = 0; k < ROWS; ++k) t += s[k];
  #pragma unroll
  for (int off = 32; off > 0; off >>= 1) t += __shfl_down(t, off);

  __shared__ float sred[4];
  if (lane == 0) sred[w] = t;
  __syncthreads();
  if (threadIdx.x == 0)
    atomicAdd(&out[b], sred[0] + sred[1] + sred[2] + sred[3]);  // 392 total
}

extern "C" void kernel_launch(void* const* d_in, const int* in_sizes, int n_in,
                              void* d_out, int out_size, void* d_ws, size_t ws_size,
                              hipStream_t stream) {
  const float* f1 = (const float*)d_in[0];   // [B, C, 14, 14]
  const float* f2 = (const float*)d_in[1];
  const float* W1 = (const float*)d_in[2];   // [2C, HID]
  const float* b1 = (const float*)d_in[3];   // [HID]
  const float* W2 = (const float*)d_in[4];   // [HID, 1]
  const float* b2 = (const float*)d_in[5];   // [1]
  float* out = (float*)d_out;                // [B, 1]

  float* p1 = (float*)d_ws;
  float* p2 = p1 + P_ELEMS;

  gemm_p_mfma<<<GEMM_BLOCKS, 256, 0, stream>>>(f1, f2, W1, b1, b2, p1, p2, out);

  pair_kernel<<<PAIR_BLOCKS, 256, 0, stream>>>(p1, p2, W2, out);
}